// Round 1
// baseline (642.832 us; speedup 1.0000x reference)
//
#include <hip/hip_runtime.h>
#include <math.h>

#define N_NODES 400000
#define N_EDGES 2400000
#define NPG 40
#define N_GRAPHS 10000
#define IN_F 30
#define H1 30
#define H2 10
#define OUTF 4

// ---------------- K1: degrees ----------------
__global__ void degree_kernel(const int* __restrict__ src, const int* __restrict__ dst,
                              float* __restrict__ deg_out, float* __restrict__ deg_in) {
    int i = blockIdx.x * blockDim.x + threadIdx.x;
    int stride = gridDim.x * blockDim.x;
    for (; i < N_EDGES; i += stride) {
        atomicAdd(&deg_out[src[i]], 1.0f);
        atomicAdd(&deg_in[dst[i]], 1.0f);
    }
}

// ---------------- K2: h = (X * norm_src) @ W ----------------
__global__ void gc1_kernel(const float* __restrict__ feat, const float* __restrict__ deg_out,
                           const float* __restrict__ W, float* __restrict__ h) {
    __shared__ float sW[IN_F * H1];
    for (int t = threadIdx.x; t < IN_F * H1; t += blockDim.x) sW[t] = W[t];
    __syncthreads();
    int i = blockIdx.x * blockDim.x + threadIdx.x;
    if (i >= N_NODES) return;
    float ns = rsqrtf(fmaxf(deg_out[i], 1.0f));
    float f[IN_F];
    #pragma unroll
    for (int k = 0; k < IN_F; k++) f[k] = feat[i * IN_F + k] * ns;
    #pragma unroll
    for (int j = 0; j < H1; j++) {
        float s = 0.f;
        #pragma unroll
        for (int k = 0; k < IN_F; k++) s += f[k] * sW[k * H1 + j];
        h[i * H1 + j] = s;
    }
}

// ---------------- K3: agg[dst] += h[src], 32 lanes per edge ----------------
__global__ void scatter_kernel(const int* __restrict__ src, const int* __restrict__ dst,
                               const float* __restrict__ h, float* __restrict__ agg) {
    unsigned long long t = (unsigned long long)blockIdx.x * blockDim.x + threadIdx.x;
    unsigned int f = (unsigned int)(t & 31ull);
    unsigned int e = (unsigned int)(t >> 5);
    if (e >= N_EDGES || f >= H1) return;
    int s = src[e];
    int d = dst[e];
    atomicAdd(&agg[(unsigned long long)d * H1 + f], h[(unsigned long long)s * H1 + f]);
}

// ---------------- K4: norm_dst + bias -> segment max -> MLP -> sigmoid ----------------
__global__ void epilogue_kernel(const float* __restrict__ agg, const float* __restrict__ deg_in,
                                const float* __restrict__ b,
                                const float* __restrict__ W2, const float* __restrict__ b2,
                                const float* __restrict__ W3, const float* __restrict__ b3,
                                float* __restrict__ out) {
    int g = blockIdx.x;
    int t = threadIdx.x;  // 64 threads
    __shared__ float sh[NPG][H1 + 1];
    __shared__ float pooled[H1];
    __shared__ float z[H2];

    if (t < NPG) {
        int node = g * NPG + t;
        float nd = rsqrtf(fmaxf(deg_in[node], 1.0f));
        #pragma unroll
        for (int j = 0; j < H1; j++) sh[t][j] = agg[(unsigned long long)node * H1 + j] * nd + b[j];
    }
    __syncthreads();
    if (t < H1) {
        float m = -INFINITY;
        #pragma unroll
        for (int n = 0; n < NPG; n++) m = fmaxf(m, sh[n][t]);
        pooled[t] = m;
    }
    __syncthreads();
    if (t < H2) {
        float s = b2[t];
        #pragma unroll
        for (int k = 0; k < H1; k++) s += pooled[k] * W2[k * H2 + t];
        z[t] = fmaxf(s, 0.f);
    }
    __syncthreads();
    if (t < OUTF) {
        float s = b3[t];
        #pragma unroll
        for (int k = 0; k < H2; k++) s += z[k] * W3[k * OUTF + t];
        out[g * OUTF + t] = 1.f / (1.f + expf(-s));
    }
}

extern "C" void kernel_launch(void* const* d_in, const int* in_sizes, int n_in,
                              void* d_out, int out_size, void* d_ws, size_t ws_size,
                              hipStream_t stream) {
    const float* feat = (const float*)d_in[0];
    const int*   src  = (const int*)d_in[1];
    const int*   dst  = (const int*)d_in[2];
    // d_in[3] = segment_ids (contiguous, node/40 — implicit), d_in[4] = num_graphs (10000)
    const float* W  = (const float*)d_in[5];
    const float* b  = (const float*)d_in[6];
    const float* W2 = (const float*)d_in[7];
    const float* b2 = (const float*)d_in[8];
    const float* W3 = (const float*)d_in[9];
    const float* b3 = (const float*)d_in[10];
    float* out = (float*)d_out;

    char* ws = (char*)d_ws;
    float* deg_out = (float*)ws;                                   // N_NODES
    float* deg_in  = deg_out + N_NODES;                            // N_NODES
    float* h       = deg_in + N_NODES;                             // N_NODES*H1
    float* agg     = h + (size_t)N_NODES * H1;                     // N_NODES*H1

    // zero deg_out, deg_in, agg (contiguous except h in the middle — two memsets)
    hipMemsetAsync(deg_out, 0, sizeof(float) * 2 * N_NODES, stream);
    hipMemsetAsync(agg, 0, sizeof(float) * (size_t)N_NODES * H1, stream);

    degree_kernel<<<2048, 256, 0, stream>>>(src, dst, deg_out, deg_in);

    gc1_kernel<<<(N_NODES + 255) / 256, 256, 0, stream>>>(feat, deg_out, W, h);

    unsigned long long scatter_threads = (unsigned long long)N_EDGES * 32ull;
    unsigned int scatter_blocks = (unsigned int)((scatter_threads + 255ull) / 256ull);
    scatter_kernel<<<scatter_blocks, 256, 0, stream>>>(src, dst, h, agg);

    epilogue_kernel<<<N_GRAPHS, 64, 0, stream>>>(agg, deg_in, b, W2, b2, W3, b3, out);
}

// Round 2
// 607.687 us; speedup vs baseline: 1.0578x; 1.0578x over previous
//
#include <hip/hip_runtime.h>
#include <math.h>

#define N_NODES 400000
#define N_EDGES 2400000
#define NPG 40
#define N_GRAPHS 10000
#define IN_F 30
#define H1 30
#define H2 10
#define OUTF 4
#define NB 391   // ceil(400000/1024) scan blocks

// ---------------- K1: integer degrees ----------------
__global__ void degree_kernel(const int* __restrict__ src, const int* __restrict__ dst,
                              int* __restrict__ deg_out, int* __restrict__ deg_in) {
    int i = blockIdx.x * blockDim.x + threadIdx.x;
    int stride = gridDim.x * blockDim.x;
    for (; i < N_EDGES; i += stride) {
        atomicAdd(&deg_out[src[i]], 1);
        atomicAdd(&deg_in[dst[i]], 1);
    }
}

// ---------------- scan (exclusive prefix sum of deg_in -> row_start) ----------------
__global__ void scan1(const int* __restrict__ deg, int* __restrict__ row_start,
                      int* __restrict__ blk_sums) {
    __shared__ int s[256];
    int t = threadIdx.x;
    int base = blockIdx.x * 1024 + t * 4;
    int v[4];
    #pragma unroll
    for (int k = 0; k < 4; k++) v[k] = (base + k < N_NODES) ? deg[base + k] : 0;
    int tsum = v[0] + v[1] + v[2] + v[3];
    s[t] = tsum;
    __syncthreads();
    for (int o = 1; o < 256; o <<= 1) {
        int y = (t >= o) ? s[t - o] : 0;
        __syncthreads();
        s[t] += y;
        __syncthreads();
    }
    int run = s[t] - tsum;  // exclusive prefix within block
    #pragma unroll
    for (int k = 0; k < 4; k++) {
        if (base + k < N_NODES) row_start[base + k] = run;
        run += v[k];
    }
    if (t == 255) blk_sums[blockIdx.x] = s[255];
}

__global__ void scan2(const int* __restrict__ blk_sums, int* __restrict__ blk_off) {
    __shared__ int s[512];
    int t = threadIdx.x;
    int v = (t < NB) ? blk_sums[t] : 0;
    s[t] = v;
    __syncthreads();
    for (int o = 1; o < 512; o <<= 1) {
        int y = (t >= o) ? s[t - o] : 0;
        __syncthreads();
        s[t] += y;
        __syncthreads();
    }
    if (t < NB) blk_off[t] = s[t] - v;
}

__global__ void scan3(int* __restrict__ row_start, int* __restrict__ cursor,
                      const int* __restrict__ blk_off) {
    int t = threadIdx.x;
    int off = blk_off[blockIdx.x];
    int base = blockIdx.x * 1024 + t * 4;
    #pragma unroll
    for (int k = 0; k < 4; k++) {
        int i = base + k;
        if (i < N_NODES) {
            int r = row_start[i] + off;
            row_start[i] = r;
            cursor[i] = r;
        }
    }
}

// ---------------- K2: CSR fill (counting-sort scatter of src ids) ----------------
__global__ void fill_kernel(const int* __restrict__ src, const int* __restrict__ dst,
                            int* __restrict__ cursor, int* __restrict__ csr_src) {
    int i = blockIdx.x * blockDim.x + threadIdx.x;
    int stride = gridDim.x * blockDim.x;
    for (; i < N_EDGES; i += stride) {
        int d = dst[i];
        int pos = atomicAdd(&cursor[d], 1);
        csr_src[pos] = src[i];
    }
}

// ---------------- K3: h = (X * norm_src) @ W ----------------
__global__ void gc1_kernel(const float* __restrict__ feat, const int* __restrict__ deg_out,
                           const float* __restrict__ W, float* __restrict__ h) {
    __shared__ float sW[IN_F * H1];
    for (int t = threadIdx.x; t < IN_F * H1; t += blockDim.x) sW[t] = W[t];
    __syncthreads();
    int i = blockIdx.x * blockDim.x + threadIdx.x;
    if (i >= N_NODES) return;
    float ns = rsqrtf(fmaxf((float)deg_out[i], 1.0f));
    float f[IN_F];
    #pragma unroll
    for (int k = 0; k < IN_F; k++) f[k] = feat[i * IN_F + k] * ns;
    #pragma unroll
    for (int j = 0; j < H1; j++) {
        float s = 0.f;
        #pragma unroll
        for (int k = 0; k < IN_F; k++) s += f[k] * sW[k * H1 + j];
        h[i * H1 + j] = s;
    }
}

// ---------------- K4: fused pull-aggregate + norm + bias + max-pool + MLP + sigmoid ----------------
// One block (256 thr) per graph. Half-wave (32 lanes) per node slice; f = lane&31 is feature.
__global__ void pull_pool_mlp(const int* __restrict__ row_start, const int* __restrict__ deg_in,
                              const int* __restrict__ csr_src, const float* __restrict__ h,
                              const float* __restrict__ b,
                              const float* __restrict__ W2, const float* __restrict__ b2,
                              const float* __restrict__ W3, const float* __restrict__ b3,
                              float* __restrict__ out) {
    int g = blockIdx.x;
    int t = threadIdx.x;     // 0..255
    int f = t & 31;          // feature lane
    int hw = t >> 5;         // half-wave 0..7
    __shared__ float smax[8][32];
    __shared__ float z[H2];

    float m = -INFINITY;
    for (int n = hw; n < NPG; n += 8) {
        int node = g * NPG + n;
        int beg = row_start[node];
        int dc = deg_in[node];
        float acc = 0.f;
        for (int j = 0; j < dc; j++) {
            int s = csr_src[beg + j];
            if (f < H1) acc += h[(size_t)s * H1 + f];
        }
        float nd = rsqrtf(fmaxf((float)dc, 1.0f));
        float val = (f < H1) ? (acc * nd + b[f]) : -INFINITY;
        m = fmaxf(m, val);
    }
    smax[hw][f] = m;
    __syncthreads();
    if (t < 32) {
        float mm = smax[0][t];
        #pragma unroll
        for (int k = 1; k < 8; k++) mm = fmaxf(mm, smax[k][t]);
        smax[0][t] = mm;     // pooled[f] for f < 30
    }
    __syncthreads();
    if (t < H2) {
        float s2 = b2[t];
        #pragma unroll
        for (int k = 0; k < H1; k++) s2 += smax[0][k] * W2[k * H2 + t];
        z[t] = fmaxf(s2, 0.f);
    }
    __syncthreads();
    if (t < OUTF) {
        float s3 = b3[t];
        #pragma unroll
        for (int k = 0; k < H2; k++) s3 += z[k] * W3[k * OUTF + t];
        out[g * OUTF + t] = 1.f / (1.f + expf(-s3));
    }
}

extern "C" void kernel_launch(void* const* d_in, const int* in_sizes, int n_in,
                              void* d_out, int out_size, void* d_ws, size_t ws_size,
                              hipStream_t stream) {
    const float* feat = (const float*)d_in[0];
    const int*   src  = (const int*)d_in[1];
    const int*   dst  = (const int*)d_in[2];
    const float* W  = (const float*)d_in[5];
    const float* b  = (const float*)d_in[6];
    const float* W2 = (const float*)d_in[7];
    const float* b2 = (const float*)d_in[8];
    const float* W3 = (const float*)d_in[9];
    const float* b3 = (const float*)d_in[10];
    float* out = (float*)d_out;

    char* ws = (char*)d_ws;
    int* deg_out   = (int*)ws;                          // N_NODES
    int* deg_in    = deg_out + N_NODES;                 // N_NODES
    int* row_start = deg_in + N_NODES;                  // N_NODES
    int* cursor    = row_start + N_NODES;               // N_NODES
    int* blk_sums  = cursor + N_NODES;                  // NB
    int* blk_off   = blk_sums + 512;                    // NB (padded)
    int* csr_src   = blk_off + 512;                     // N_EDGES
    float* h       = (float*)(csr_src + N_EDGES);       // N_NODES*H1 (+pad)

    hipMemsetAsync(deg_out, 0, sizeof(int) * 2 * N_NODES, stream);

    degree_kernel<<<2048, 256, 0, stream>>>(src, dst, deg_out, deg_in);

    scan1<<<NB, 256, 0, stream>>>(deg_in, row_start, blk_sums);
    scan2<<<1, 512, 0, stream>>>(blk_sums, blk_off);
    scan3<<<NB, 256, 0, stream>>>(row_start, cursor, blk_off);

    fill_kernel<<<2048, 256, 0, stream>>>(src, dst, cursor, csr_src);

    gc1_kernel<<<(N_NODES + 255) / 256, 256, 0, stream>>>(feat, deg_out, W, h);

    pull_pool_mlp<<<N_GRAPHS, 256, 0, stream>>>(row_start, deg_in, csr_src, h,
                                                b, W2, b2, W3, b3, out);
}